// Round 5
// baseline (174.375 us; speedup 1.0000x reference)
//
#include <hip/hip_runtime.h>
#include <hip/hip_bf16.h>

#define BB 4
#define CIN 256      // CK == CQ == CV
#define CO 64
#define NN 576       // 24*24
#define NKC 18       // 576/32 k-chunks
#define NQT 36       // q-subtiles of 16

typedef __attribute__((ext_vector_type(8))) short short8;
typedef __attribute__((ext_vector_type(4))) float floatx4;

__device__ __forceinline__ unsigned short f2bf(float f) {
    unsigned int u = __float_as_uint(f);
    unsigned int r = (u + 0x7fffu + ((u >> 16) & 1u)) >> 16;   // RNE
    return (unsigned short)r;
}

// ------------------------------------------------------------------
// K1: fused prep.
//  bids [0,288):   proj+exp for (z,b,nt): e[b,n,o]=exp(2*(sum_c x[b,c,n]W[o,c]+bias[o]))
//                  via MFMA D[o][n] = W (A-frag, direct) x X (B-frag, direct from global).
//                  k-split 4 across waves, LDS reduce, exp, coalesced store.
//  bids [288,576): value -> Vp A-fragments (4 frag-units per block, one per wave).
__global__ void __launch_bounds__(256) prep_kernel(
    const float* __restrict__ key, const float* __restrict__ query,
    const float* __restrict__ value,
    const float* __restrict__ Wk, const float* __restrict__ Wq,
    const float* __restrict__ bk, const float* __restrict__ bq,
    float* __restrict__ ek, float* __restrict__ eq,
    unsigned short* __restrict__ Vp)
{
    __shared__ float red[4][4][64][4];   // [wave][mt][lane][reg] 16 KB
    __shared__ float ex[16 * 69];        // [n_local][o] padded

    int bid = blockIdx.x;
    int t = threadIdx.x;
    int l = t & 63;
    int w = __builtin_amdgcn_readfirstlane(t >> 6);

    if (bid < 288) {
        int z  = bid / 144;
        int r  = bid % 144;
        int b  = r / 36;
        int nt = r % 36;
        int n0 = nt * 16;
        const float* x = z ? query : key;
        const float* W = z ? Wq : Wk;

        floatx4 acc[4] = {{0.f,0.f,0.f,0.f},{0.f,0.f,0.f,0.f},
                          {0.f,0.f,0.f,0.f},{0.f,0.f,0.f,0.f}};

        #pragma unroll
        for (int kci = 0; kci < 2; ++kci) {
            int kc = w + kci * 4;                    // 0..7
            int cbase = kc * 32 + (l >> 4) * 8;
            // x B-frag direct from global: elem j = x[b][cbase+j][n0+(l&15)]
            const float* xp = x + ((size_t)b * CIN + cbase) * NN + n0 + (l & 15);
            uint4 bu;
            {
                float x0 = xp[0 * NN], x1 = xp[1 * NN], x2 = xp[2 * NN], x3 = xp[3 * NN];
                float x4 = xp[4 * NN], x5 = xp[5 * NN], x6 = xp[6 * NN], x7 = xp[7 * NN];
                bu.x = (unsigned)f2bf(x0) | ((unsigned)f2bf(x1) << 16);
                bu.y = (unsigned)f2bf(x2) | ((unsigned)f2bf(x3) << 16);
                bu.z = (unsigned)f2bf(x4) | ((unsigned)f2bf(x5) << 16);
                bu.w = (unsigned)f2bf(x6) | ((unsigned)f2bf(x7) << 16);
            }
            short8 bx = *(short8*)&bu;
            #pragma unroll
            for (int mt = 0; mt < 4; ++mt) {
                const float4* wp = (const float4*)(W + (size_t)(mt * 16 + (l & 15)) * CIN + cbase);
                float4 w0 = wp[0], w1 = wp[1];
                uint4 au;
                au.x = (unsigned)f2bf(w0.x) | ((unsigned)f2bf(w0.y) << 16);
                au.y = (unsigned)f2bf(w0.z) | ((unsigned)f2bf(w0.w) << 16);
                au.z = (unsigned)f2bf(w1.x) | ((unsigned)f2bf(w1.y) << 16);
                au.w = (unsigned)f2bf(w1.z) | ((unsigned)f2bf(w1.w) << 16);
                acc[mt] = __builtin_amdgcn_mfma_f32_16x16x32_bf16(*(short8*)&au, bx, acc[mt], 0, 0, 0);
            }
        }
        #pragma unroll
        for (int mt = 0; mt < 4; ++mt)
            #pragma unroll
            for (int rr = 0; rr < 4; ++rr)
                red[w][mt][l][rr] = acc[mt][rr];
        __syncthreads();

        // wave w finalizes mt = w: D[o][n], o = w*16+(l>>4)*4+r, n = n0+(l&15)
        const float* bias = z ? bq : bk;
        #pragma unroll
        for (int rr = 0; rr < 4; ++rr) {
            float v = red[0][w][l][rr] + red[1][w][l][rr]
                    + red[2][w][l][rr] + red[3][w][l][rr];
            int o = w * 16 + (l >> 4) * 4 + rr;
            ex[(l & 15) * 69 + o] = __expf(2.0f * (v + bias[o]));
        }
        __syncthreads();

        float* outp = z ? eq : ek;
        float* obase = outp + ((size_t)b * NN + n0) * CO;
        #pragma unroll
        for (int i = 0; i < 4; ++i) {
            int idx = t + i * 256;           // 0..1023
            int n = idx >> 6, o = idx & 63;
            obase[(size_t)n * CO + o] = ex[n * 69 + o];
        }
    } else {
        // ---- V pack: 4 fragment-units per block ----
        int funit = (bid - 288) * 4 + w;     // 0..1151
        int b  = funit / 288;
        int r2 = funit % 288;
        int ct = r2 / NKC;
        int kc = r2 % NKC;
        int c = ct * 16 + (l & 15);
        int k = kc * 32 + (l >> 4) * 8;
        const float4* p = (const float4*)(value + ((size_t)b * CIN + c) * NN + k);
        float4 v0 = p[0], v1 = p[1];
        uint4 u;
        u.x = (unsigned)f2bf(v0.x) | ((unsigned)f2bf(v0.y) << 16);
        u.y = (unsigned)f2bf(v0.z) | ((unsigned)f2bf(v0.w) << 16);
        u.z = (unsigned)f2bf(v1.x) | ((unsigned)f2bf(v1.y) << 16);
        u.w = (unsigned)f2bf(v1.z) | ((unsigned)f2bf(v1.w) << 16);
        *(uint4*)(Vp + (((size_t)b * 16 + ct) * NKC + kc) * 512 + l * 8) = u;
    }
}

// ------------------------------------------------------------------
// K2: attn scores + sigmoid + bf16 B-fragment pack.
// score(k,q) = C - sum_o 2wf[o]/(1 + ek[k,o]*eq[q,o]),  C = sum wf + bf.
// eq row per-lane in VGPRs (64); ek tile + 2wf in LDS (broadcast b128 reads).
// grid: (NN/64, NN/32, BB), block 256 = 4 waves (wave w -> 8 k).
__global__ void __launch_bounds__(256, 4) attn_pack_kernel(
    const float* __restrict__ ek, const float* __restrict__ eq,
    const float* __restrict__ wf, const float* __restrict__ bfp,
    unsigned short* __restrict__ Bp)
{
    int b  = blockIdx.z;
    int k0 = blockIdx.y * 32;
    int q0 = blockIdx.x * 64;
    int t  = threadIdx.x;
    int l  = t & 63;
    int w  = __builtin_amdgcn_readfirstlane(t >> 6);

    __shared__ float eqs[64 * 65];   // staging for per-lane q rows
    __shared__ float eks[32 * 68];   // k rows, 16B-aligned rows (272 B)
    __shared__ float w2s[64];
    __shared__ float Cs;
    __shared__ float sc[32 * 65];

    // stage eq tile (16 KB contiguous) coalesced
    const float4* esrc = (const float4*)(eq + ((size_t)b * NN + q0) * CO);
    #pragma unroll
    for (int i = 0; i < 4; ++i) {
        int f4 = t + i * 256;
        int row = f4 >> 4, c4 = (f4 & 15) * 4;
        float4 v = esrc[f4];
        int a = row * 65 + c4;
        eqs[a] = v.x; eqs[a + 1] = v.y; eqs[a + 2] = v.z; eqs[a + 3] = v.w;
    }
    // stage ek tile (8 KB) coalesced, 16B-aligned rows for b128 broadcast
    const float4* ksrc = (const float4*)(ek + ((size_t)b * NN + k0) * CO);
    #pragma unroll
    for (int i = 0; i < 2; ++i) {
        int f4 = t + i * 256;
        int row = f4 >> 4, c4 = (f4 & 15) * 4;
        *(float4*)&eks[row * 68 + c4] = ksrc[f4];
    }
    if (t < 64) {
        float v = wf[t];
        w2s[t] = 2.0f * v;
        #pragma unroll
        for (int s = 32; s; s >>= 1) v += __shfl_xor(v, s, 64);
        if (t == 0) Cs = v + bfp[0];
    }
    __syncthreads();

    float C = Cs;
    // per-lane q row -> VGPRs (64), conflict-free (stride-65 b32)
    float4 eqv[16];
    #pragma unroll
    for (int i = 0; i < 16; ++i) {
        int a = l * 65 + i * 4;
        eqv[i].x = eqs[a]; eqv[i].y = eqs[a + 1];
        eqv[i].z = eqs[a + 2]; eqv[i].w = eqs[a + 3];
    }

    #pragma unroll 1
    for (int kk = 0; kk < 8; ++kk) {
        int krow = w * 8 + kk;
        const float* ekr = &eks[krow * 68];
        float a0 = 0.f, a1 = 0.f, a2 = 0.f, a3 = 0.f;
        #pragma unroll
        for (int i = 0; i < 16; ++i) {
            float4 k4 = *(const float4*)(ekr + i * 4);      // LDS broadcast
            float4 w4 = *(const float4*)&w2s[i * 4];        // LDS broadcast
            float4 e4 = eqv[i];
            a0 = fmaf(w4.x, __builtin_amdgcn_rcpf(fmaf(k4.x, e4.x, 1.0f)), a0);
            a1 = fmaf(w4.y, __builtin_amdgcn_rcpf(fmaf(k4.y, e4.y, 1.0f)), a1);
            a2 = fmaf(w4.z, __builtin_amdgcn_rcpf(fmaf(k4.z, e4.z, 1.0f)), a2);
            a3 = fmaf(w4.w, __builtin_amdgcn_rcpf(fmaf(k4.w, e4.w, 1.0f)), a3);
        }
        float score = C - (a0 + a1) - (a2 + a3);
        float sg = __builtin_amdgcn_rcpf(1.0f + __expf(-score));
        sc[krow * 65 + l] = sg;
    }
    __syncthreads();

    // pack: wave w -> q-subtile w; fragment elem j = sc[(l>>4)*8+j][w*16+(l&15)]
    int col = w * 16 + (l & 15);
    int row = (l >> 4) * 8;
    uint4 o;
    o.x = (unsigned)f2bf(sc[(row + 0) * 65 + col]) | ((unsigned)f2bf(sc[(row + 1) * 65 + col]) << 16);
    o.y = (unsigned)f2bf(sc[(row + 2) * 65 + col]) | ((unsigned)f2bf(sc[(row + 3) * 65 + col]) << 16);
    o.z = (unsigned)f2bf(sc[(row + 4) * 65 + col]) | ((unsigned)f2bf(sc[(row + 5) * 65 + col]) << 16);
    o.w = (unsigned)f2bf(sc[(row + 6) * 65 + col]) | ((unsigned)f2bf(sc[(row + 7) * 65 + col]) << 16);
    size_t qt = (size_t)blockIdx.x * 4 + w;
    *(uint4*)(Bp + (((size_t)b * NQT + qt) * NKC + blockIdx.y) * 512 + l * 8) = o;
}

// ------------------------------------------------------------------
// K3: out[b,c,q] = sum_k V[b,c,k]*attn[b,k,q] via mfma_f32_16x16x32_bf16.
// block 256 = 4 waves; tile 16c x 64q; wave w takes kc = w, w+4, ...; LDS reduce.
// grid: (NN/64, 16, BB)
__global__ void __launch_bounds__(256) av_mfma_kernel(
    const unsigned short* __restrict__ Vp,
    const unsigned short* __restrict__ Bp,
    float* __restrict__ out)
{
    int b  = blockIdx.z;
    int ct = blockIdx.y;
    int qx = blockIdx.x;
    int t  = threadIdx.x;
    int l  = t & 63;
    int w  = __builtin_amdgcn_readfirstlane(t >> 6);

    floatx4 acc[4] = {{0.f,0.f,0.f,0.f},{0.f,0.f,0.f,0.f},
                      {0.f,0.f,0.f,0.f},{0.f,0.f,0.f,0.f}};

    const unsigned short* abase = Vp + ((size_t)b * 16 + ct) * NKC * 512 + l * 8;
    const unsigned short* bbase = Bp + ((size_t)b * NQT + (size_t)qx * 4) * NKC * 512 + l * 8;

    for (int kc = w; kc < NKC; kc += 4) {
        short8 a = *(const short8*)(abase + (size_t)kc * 512);
        #pragma unroll
        for (int qt = 0; qt < 4; ++qt) {
            short8 bq = *(const short8*)(bbase + ((size_t)qt * NKC + kc) * 512);
            acc[qt] = __builtin_amdgcn_mfma_f32_16x16x32_bf16(a, bq, acc[qt], 0, 0, 0);
        }
    }

    __shared__ float red[4][64][17];
    #pragma unroll
    for (int qt = 0; qt < 4; ++qt)
        #pragma unroll
        for (int r = 0; r < 4; ++r)
            red[w][l][qt * 4 + r] = acc[qt][r];
    __syncthreads();

    int q = qx * 64 + w * 16 + (l & 15);
    #pragma unroll
    for (int r = 0; r < 4; ++r) {
        float s = red[0][l][w * 4 + r] + red[1][l][w * 4 + r]
                + red[2][l][w * 4 + r] + red[3][l][w * 4 + r];
        int c = ct * 16 + (l >> 4) * 4 + r;
        out[((size_t)b * CIN + c) * NN + q] = s;
    }
}

// ------------------------------------------------------------------
extern "C" void kernel_launch(void* const* d_in, const int* in_sizes, int n_in,
                              void* d_out, int out_size, void* d_ws, size_t ws_size,
                              hipStream_t stream) {
    const float* key   = (const float*)d_in[0];
    const float* query = (const float*)d_in[1];
    const float* value = (const float*)d_in[2];
    const float* Wk    = (const float*)d_in[3];
    const float* bk    = (const float*)d_in[4];
    const float* Wq    = (const float*)d_in[5];
    const float* bq    = (const float*)d_in[6];
    const float* wf    = (const float*)d_in[7];
    const float* bf    = (const float*)d_in[8];
    float* out = (float*)d_out;

    float* ws = (float*)d_ws;
    float* ek = ws;                                        // 147456 f
    float* eq = ek + (size_t)BB * NN * CO;                 // 147456 f
    unsigned short* Vp = (unsigned short*)(eq + (size_t)BB * NN * CO); // 589824 us
    unsigned short* Bp = Vp + (size_t)BB * 16 * NKC * 512;             // 1327104 us

    prep_kernel<<<576, 256, 0, stream>>>(key, query, value, Wk, Wq, bk, bq, ek, eq, Vp);

    dim3 ga(NN / 64, NN / 32, BB);
    attn_pack_kernel<<<ga, 256, 0, stream>>>(ek, eq, wf, bf, Bp);

    dim3 gm(NN / 64, 16, BB);
    av_mfma_kernel<<<gm, 256, 0, stream>>>(Vp, Bp, out);
}

// Round 6
// 108.086 us; speedup vs baseline: 1.6133x; 1.6133x over previous
//
#include <hip/hip_runtime.h>
#include <hip/hip_bf16.h>

#define BB 4
#define CIN 256      // CK == CQ == CV
#define CO 64
#define NN 576       // 24*24
#define NKC 18       // 576/32 k-chunks
#define NQT 36       // q-subtiles of 16

typedef __attribute__((ext_vector_type(8))) short short8;
typedef __attribute__((ext_vector_type(4))) float floatx4;

__device__ __forceinline__ unsigned short f2bf(float f) {
    unsigned int u = __float_as_uint(f);
    unsigned int r = (u + 0x7fffu + ((u >> 16) & 1u)) >> 16;   // RNE
    return (unsigned short)r;
}

// ------------------------------------------------------------------
// K1: fused prep.
//  bids [0,288):   proj+exp for (z,b,nt): e[b,n,o]=exp(2*(sum_c x[b,c,n]W[o,c]+bias[o]))
//                  via MFMA D[o][n] = W (A-frag, direct) x X (B-frag, direct from global).
//                  k-split 4 across waves, LDS reduce, exp, coalesced store.
//  bids [288,576): value -> Vp A-fragments (4 frag-units per block, one per wave).
__global__ void __launch_bounds__(256) prep_kernel(
    const float* __restrict__ key, const float* __restrict__ query,
    const float* __restrict__ value,
    const float* __restrict__ Wk, const float* __restrict__ Wq,
    const float* __restrict__ bk, const float* __restrict__ bq,
    float* __restrict__ ek, float* __restrict__ eq,
    unsigned short* __restrict__ Vp)
{
    __shared__ float red[4][4][64][4];   // [wave][mt][lane][reg] 16 KB
    __shared__ float ex[16 * 69];        // [n_local][o] padded

    int bid = blockIdx.x;
    int t = threadIdx.x;
    int l = t & 63;
    int w = __builtin_amdgcn_readfirstlane(t >> 6);

    if (bid < 288) {
        int z  = bid / 144;
        int r  = bid % 144;
        int b  = r / 36;
        int nt = r % 36;
        int n0 = nt * 16;
        const float* x = z ? query : key;
        const float* W = z ? Wq : Wk;

        floatx4 acc[4] = {{0.f,0.f,0.f,0.f},{0.f,0.f,0.f,0.f},
                          {0.f,0.f,0.f,0.f},{0.f,0.f,0.f,0.f}};

        #pragma unroll
        for (int kci = 0; kci < 2; ++kci) {
            int kc = w + kci * 4;                    // 0..7
            int cbase = kc * 32 + (l >> 4) * 8;
            // x B-frag direct from global: elem j = x[b][cbase+j][n0+(l&15)]
            const float* xp = x + ((size_t)b * CIN + cbase) * NN + n0 + (l & 15);
            uint4 bu;
            {
                float x0 = xp[0 * NN], x1 = xp[1 * NN], x2 = xp[2 * NN], x3 = xp[3 * NN];
                float x4 = xp[4 * NN], x5 = xp[5 * NN], x6 = xp[6 * NN], x7 = xp[7 * NN];
                bu.x = (unsigned)f2bf(x0) | ((unsigned)f2bf(x1) << 16);
                bu.y = (unsigned)f2bf(x2) | ((unsigned)f2bf(x3) << 16);
                bu.z = (unsigned)f2bf(x4) | ((unsigned)f2bf(x5) << 16);
                bu.w = (unsigned)f2bf(x6) | ((unsigned)f2bf(x7) << 16);
            }
            short8 bx = *(short8*)&bu;
            #pragma unroll
            for (int mt = 0; mt < 4; ++mt) {
                const float4* wp = (const float4*)(W + (size_t)(mt * 16 + (l & 15)) * CIN + cbase);
                float4 w0 = wp[0], w1 = wp[1];
                uint4 au;
                au.x = (unsigned)f2bf(w0.x) | ((unsigned)f2bf(w0.y) << 16);
                au.y = (unsigned)f2bf(w0.z) | ((unsigned)f2bf(w0.w) << 16);
                au.z = (unsigned)f2bf(w1.x) | ((unsigned)f2bf(w1.y) << 16);
                au.w = (unsigned)f2bf(w1.z) | ((unsigned)f2bf(w1.w) << 16);
                acc[mt] = __builtin_amdgcn_mfma_f32_16x16x32_bf16(*(short8*)&au, bx, acc[mt], 0, 0, 0);
            }
        }
        #pragma unroll
        for (int mt = 0; mt < 4; ++mt)
            #pragma unroll
            for (int rr = 0; rr < 4; ++rr)
                red[w][mt][l][rr] = acc[mt][rr];
        __syncthreads();

        // wave w finalizes mt = w: D[o][n], o = w*16+(l>>4)*4+r, n = n0+(l&15)
        const float* bias = z ? bq : bk;
        #pragma unroll
        for (int rr = 0; rr < 4; ++rr) {
            float v = red[0][w][l][rr] + red[1][w][l][rr]
                    + red[2][w][l][rr] + red[3][w][l][rr];
            int o = w * 16 + (l >> 4) * 4 + rr;
            ex[(l & 15) * 69 + o] = __expf(2.0f * (v + bias[o]));
        }
        __syncthreads();

        float* outp = z ? eq : ek;
        float* obase = outp + ((size_t)b * NN + n0) * CO;
        #pragma unroll
        for (int i = 0; i < 4; ++i) {
            int idx = t + i * 256;           // 0..1023
            int n = idx >> 6, o = idx & 63;
            obase[(size_t)n * CO + o] = ex[n * 69 + o];
        }
    } else {
        // ---- V pack: 4 fragment-units per block ----
        int funit = (bid - 288) * 4 + w;     // 0..1151
        int b  = funit / 288;
        int r2 = funit % 288;
        int ct = r2 / NKC;
        int kc = r2 % NKC;
        int c = ct * 16 + (l & 15);
        int k = kc * 32 + (l >> 4) * 8;
        const float4* p = (const float4*)(value + ((size_t)b * CIN + c) * NN + k);
        float4 v0 = p[0], v1 = p[1];
        uint4 u;
        u.x = (unsigned)f2bf(v0.x) | ((unsigned)f2bf(v0.y) << 16);
        u.y = (unsigned)f2bf(v0.z) | ((unsigned)f2bf(v0.w) << 16);
        u.z = (unsigned)f2bf(v1.x) | ((unsigned)f2bf(v1.y) << 16);
        u.w = (unsigned)f2bf(v1.z) | ((unsigned)f2bf(v1.w) << 16);
        *(uint4*)(Vp + (((size_t)b * 16 + ct) * NKC + kc) * 512 + l * 8) = u;
    }
}

// ------------------------------------------------------------------
// K2: attn scores + sigmoid + bf16 B-fragment pack.
// score(k,q) = C - sum_o 2wf[o]/(1 + ek[k,o]*eq[q,o]),  C = sum wf + bf.
// eq row per-lane in VGPRs (64 regs); ek tile + 2wf in LDS (broadcast reads).
// __launch_bounds__(256,3): VGPR cap ~170 — (256,4) spilled eqv (R5: 200MB
// scratch FETCH, 91 us). grid: (NN/64, NN/32, BB), block 256 = 4 waves.
__global__ void __launch_bounds__(256, 3) attn_pack_kernel(
    const float* __restrict__ ek, const float* __restrict__ eq,
    const float* __restrict__ wf, const float* __restrict__ bfp,
    unsigned short* __restrict__ Bp)
{
    int b  = blockIdx.z;
    int k0 = blockIdx.y * 32;
    int q0 = blockIdx.x * 64;
    int t  = threadIdx.x;
    int l  = t & 63;
    int w  = __builtin_amdgcn_readfirstlane(t >> 6);

    __shared__ float eqs[64 * 65];   // staging for per-lane q rows
    __shared__ float eks[32 * 68];   // k rows, 16B-aligned rows (272 B)
    __shared__ float w2s[64];
    __shared__ float Cs;
    __shared__ float sc[32 * 65];

    // stage eq tile (16 KB contiguous) coalesced
    const float4* esrc = (const float4*)(eq + ((size_t)b * NN + q0) * CO);
    #pragma unroll
    for (int i = 0; i < 4; ++i) {
        int f4 = t + i * 256;
        int row = f4 >> 4, c4 = (f4 & 15) * 4;
        float4 v = esrc[f4];
        int a = row * 65 + c4;
        eqs[a] = v.x; eqs[a + 1] = v.y; eqs[a + 2] = v.z; eqs[a + 3] = v.w;
    }
    // stage ek tile (8 KB) coalesced, 16B-aligned rows for b128 broadcast
    const float4* ksrc = (const float4*)(ek + ((size_t)b * NN + k0) * CO);
    #pragma unroll
    for (int i = 0; i < 2; ++i) {
        int f4 = t + i * 256;
        int row = f4 >> 4, c4 = (f4 & 15) * 4;
        *(float4*)&eks[row * 68 + c4] = ksrc[f4];
    }
    if (t < 64) {
        float v = wf[t];
        w2s[t] = 2.0f * v;
        #pragma unroll
        for (int s = 32; s; s >>= 1) v += __shfl_xor(v, s, 64);
        if (t == 0) Cs = v + bfp[0];
    }
    __syncthreads();

    float C = Cs;
    // per-lane q row -> VGPRs (64), conflict-free (stride-65 b32)
    float4 eqv[16];
    #pragma unroll
    for (int i = 0; i < 16; ++i) {
        int a = l * 65 + i * 4;
        eqv[i].x = eqs[a]; eqv[i].y = eqs[a + 1];
        eqv[i].z = eqs[a + 2]; eqv[i].w = eqs[a + 3];
    }

    #pragma unroll 1
    for (int kk = 0; kk < 8; ++kk) {
        int krow = w * 8 + kk;
        const float* ekr = &eks[krow * 68];
        float a0 = 0.f, a1 = 0.f, a2 = 0.f, a3 = 0.f;
        #pragma unroll
        for (int i = 0; i < 16; ++i) {
            float4 k4 = *(const float4*)(ekr + i * 4);      // LDS broadcast
            float4 w4 = *(const float4*)&w2s[i * 4];        // LDS broadcast
            float4 e4 = eqv[i];
            a0 = fmaf(w4.x, __builtin_amdgcn_rcpf(fmaf(k4.x, e4.x, 1.0f)), a0);
            a1 = fmaf(w4.y, __builtin_amdgcn_rcpf(fmaf(k4.y, e4.y, 1.0f)), a1);
            a2 = fmaf(w4.z, __builtin_amdgcn_rcpf(fmaf(k4.z, e4.z, 1.0f)), a2);
            a3 = fmaf(w4.w, __builtin_amdgcn_rcpf(fmaf(k4.w, e4.w, 1.0f)), a3);
        }
        float score = C - (a0 + a1) - (a2 + a3);
        float sg = __builtin_amdgcn_rcpf(1.0f + __expf(-score));
        sc[krow * 65 + l] = sg;
    }
    __syncthreads();

    // pack: wave w -> q-subtile w; fragment elem j = sc[(l>>4)*8+j][w*16+(l&15)]
    int col = w * 16 + (l & 15);
    int row = (l >> 4) * 8;
    uint4 o;
    o.x = (unsigned)f2bf(sc[(row + 0) * 65 + col]) | ((unsigned)f2bf(sc[(row + 1) * 65 + col]) << 16);
    o.y = (unsigned)f2bf(sc[(row + 2) * 65 + col]) | ((unsigned)f2bf(sc[(row + 3) * 65 + col]) << 16);
    o.z = (unsigned)f2bf(sc[(row + 4) * 65 + col]) | ((unsigned)f2bf(sc[(row + 5) * 65 + col]) << 16);
    o.w = (unsigned)f2bf(sc[(row + 6) * 65 + col]) | ((unsigned)f2bf(sc[(row + 7) * 65 + col]) << 16);
    size_t qt = (size_t)blockIdx.x * 4 + w;
    *(uint4*)(Bp + (((size_t)b * NQT + qt) * NKC + blockIdx.y) * 512 + l * 8) = o;
}

// ------------------------------------------------------------------
// K3: out[b,c,q] = sum_k V[b,c,k]*attn[b,k,q] via mfma_f32_16x16x32_bf16.
// block 256 = 4 waves; tile 16c x 64q; wave w takes kc = w, w+4, ...; LDS reduce.
// grid: (NN/64, 16, BB)
__global__ void __launch_bounds__(256) av_mfma_kernel(
    const unsigned short* __restrict__ Vp,
    const unsigned short* __restrict__ Bp,
    float* __restrict__ out)
{
    int b  = blockIdx.z;
    int ct = blockIdx.y;
    int qx = blockIdx.x;
    int t  = threadIdx.x;
    int l  = t & 63;
    int w  = __builtin_amdgcn_readfirstlane(t >> 6);

    floatx4 acc[4] = {{0.f,0.f,0.f,0.f},{0.f,0.f,0.f,0.f},
                      {0.f,0.f,0.f,0.f},{0.f,0.f,0.f,0.f}};

    const unsigned short* abase = Vp + ((size_t)b * 16 + ct) * NKC * 512 + l * 8;
    const unsigned short* bbase = Bp + ((size_t)b * NQT + (size_t)qx * 4) * NKC * 512 + l * 8;

    for (int kc = w; kc < NKC; kc += 4) {
        short8 a = *(const short8*)(abase + (size_t)kc * 512);
        #pragma unroll
        for (int qt = 0; qt < 4; ++qt) {
            short8 bq = *(const short8*)(bbase + ((size_t)qt * NKC + kc) * 512);
            acc[qt] = __builtin_amdgcn_mfma_f32_16x16x32_bf16(a, bq, acc[qt], 0, 0, 0);
        }
    }

    __shared__ float red[4][64][17];
    #pragma unroll
    for (int qt = 0; qt < 4; ++qt)
        #pragma unroll
        for (int r = 0; r < 4; ++r)
            red[w][l][qt * 4 + r] = acc[qt][r];
    __syncthreads();

    int q = qx * 64 + w * 16 + (l & 15);
    #pragma unroll
    for (int r = 0; r < 4; ++r) {
        float s = red[0][l][w * 4 + r] + red[1][l][w * 4 + r]
                + red[2][l][w * 4 + r] + red[3][l][w * 4 + r];
        int c = ct * 16 + (l >> 4) * 4 + r;
        out[((size_t)b * CIN + c) * NN + q] = s;
    }
}

// ------------------------------------------------------------------
extern "C" void kernel_launch(void* const* d_in, const int* in_sizes, int n_in,
                              void* d_out, int out_size, void* d_ws, size_t ws_size,
                              hipStream_t stream) {
    const float* key   = (const float*)d_in[0];
    const float* query = (const float*)d_in[1];
    const float* value = (const float*)d_in[2];
    const float* Wk    = (const float*)d_in[3];
    const float* bk    = (const float*)d_in[4];
    const float* Wq    = (const float*)d_in[5];
    const float* bq    = (const float*)d_in[6];
    const float* wf    = (const float*)d_in[7];
    const float* bf    = (const float*)d_in[8];
    float* out = (float*)d_out;

    float* ws = (float*)d_ws;
    float* ek = ws;                                        // 147456 f
    float* eq = ek + (size_t)BB * NN * CO;                 // 147456 f
    unsigned short* Vp = (unsigned short*)(eq + (size_t)BB * NN * CO); // 589824 us
    unsigned short* Bp = Vp + (size_t)BB * 16 * NKC * 512;             // 1327104 us

    prep_kernel<<<576, 256, 0, stream>>>(key, query, value, Wk, Wq, bk, bq, ek, eq, Vp);

    dim3 ga(NN / 64, NN / 32, BB);
    attn_pack_kernel<<<ga, 256, 0, stream>>>(ek, eq, wf, bf, Bp);

    dim3 gm(NN / 64, 16, BB);
    av_mfma_kernel<<<gm, 256, 0, stream>>>(Vp, Bp, out);
}